// Round 1
// baseline (552.237 us; speedup 1.0000x reference)
//
#include <hip/hip_runtime.h>
#include <math.h>

#define NB    4
#define NCLS  5
#define NSHOT 5
#define NQ    75
#define CH    640
#define HW    100
#define SLICE (CH*HW)          // 64000
#define TEMP_INV 4.0f
#define EPSN  1e-12f

// workspace float offsets
#define OFF_PROTO 0            // 1,280,000
#define OFF_PINV  1280000      // 2,000
#define OFF_PBAR  1282000      // 12,800
#define OFF_QINV  1294800      // 30,000
#define OFF_QBAR  1324800      // 192,000
#define OFF_AP    1516800      // 150,000
#define OFF_AQ    1666800      // 150,000
// total = 1,816,800 floats = 7.27 MB

// K1: proto[bn, cc, i] = mean over K shots of fspt
__global__ void k_proto(const float* __restrict__ fspt, float* __restrict__ proto) {
    int v = blockIdx.x * 256 + threadIdx.x;      // float4 index, 320000 total
    if (v >= (NB*NCLS*SLICE)/4) return;
    int p  = v * 4;
    int bn = p / SLICE;
    int off = p - bn * SLICE;
    int b = bn / NCLS, n = bn - b * NCLS;
    size_t base = (size_t)(b * NCLS * NSHOT + n * NSHOT) * SLICE + off;
    float4 a = *reinterpret_cast<const float4*>(fspt + base);
    for (int k = 1; k < NSHOT; k++) {
        float4 x = *reinterpret_cast<const float4*>(fspt + base + (size_t)k * SLICE);
        a.x += x.x; a.y += x.y; a.z += x.z; a.w += x.w;
    }
    a.x *= 0.2f; a.y *= 0.2f; a.z *= 0.2f; a.w *= 0.2f;
    *reinterpret_cast<float4*>(proto + p) = a;
}

// K2: per-slice stats. inv[s*HW+i] = 1/max(||x[:,i]||,eps); bar[s*CH+cc] = mean_i x[cc,i]*inv[i]
__global__ void k_stats(const float* __restrict__ src, float* __restrict__ inv,
                        float* __restrict__ bar) {
    __shared__ float inv_s[HW];
    int s = blockIdx.x;
    int t = threadIdx.x;
    const float* base = src + (size_t)s * SLICE;
    if (t < HW) {
        float acc = 0.f;
        for (int cc = 0; cc < CH; cc++) { float x = base[cc * HW + t]; acc += x * x; }
        float iv = 1.0f / fmaxf(sqrtf(acc), EPSN);
        inv_s[t] = iv;
        inv[s * HW + t] = iv;
    }
    __syncthreads();
    for (int cc = t; cc < CH; cc += 256) {
        float acc = 0.f;
        const float* r = base + cc * HW;
        for (int i = 0; i < HW; i++) acc += r[i] * inv_s[i];
        bar[s * CH + cc] = acc * (1.0f / HW);
    }
}

// block softmax helper over first HW threads; returns e and denom via pointers
// K3: ap[bqn, i] = softmax_i( pinv[bn,i]*4 * sum_c proto[bn,c,i]*qbar[bq,c] ) + 1
__global__ void k_ap(const float* __restrict__ proto, const float* __restrict__ pinv,
                     const float* __restrict__ qbar, float* __restrict__ ap) {
    __shared__ float qb_s[CH];
    __shared__ float red_s[256];
    int blk = blockIdx.x;            // (b*NCLS+n)*15 + qg
    int qg = blk % 15;
    int bn = blk / 15;
    int b = bn / NCLS, n = bn - b * NCLS;
    int t = threadIdx.x;
    const float* pbase = proto + (size_t)bn * SLICE;
    float piv = (t < HW) ? pinv[bn * HW + t] * TEMP_INV : 0.f;
    for (int qq = 0; qq < 5; qq++) {
        int q  = qg * 5 + qq;
        int bq = b * NQ + q;
        int bqn = bq * NCLS + n;
        for (int cc = t; cc < CH; cc += 256) qb_s[cc] = qbar[bq * CH + cc];
        __syncthreads();
        float sv = 0.f;
        if (t < HW) {
            for (int cc = 0; cc < CH; cc++) sv += pbase[cc * HW + t] * qb_s[cc];
            sv *= piv;
        }
        red_s[t] = (t < HW) ? sv : -INFINITY;
        __syncthreads();
        for (int o = 128; o >= 1; o >>= 1) {
            if (t < o) red_s[t] = fmaxf(red_s[t], red_s[t + o]);
            __syncthreads();
        }
        float mx = red_s[0];
        __syncthreads();
        float e = (t < HW) ? __expf(sv - mx) : 0.f;
        red_s[t] = e;
        __syncthreads();
        for (int o = 128; o >= 1; o >>= 1) {
            if (t < o) red_s[t] += red_s[t + o];
            __syncthreads();
        }
        float denom = red_s[0];
        __syncthreads();
        if (t < HW) ap[(size_t)bqn * HW + t] = e / denom + 1.0f;
        __syncthreads();
    }
}

// K4: aq[bqn, j] = softmax_j( qinv[bq,j]*4 * sum_c pbar[bn,c]*fqry[bq,c,j] ) + 1
__global__ void k_aq(const float* __restrict__ fqry, const float* __restrict__ qinv,
                     const float* __restrict__ pbar, float* __restrict__ aq) {
    __shared__ float pb_s[CH];
    __shared__ float red_s[256];
    int bq = blockIdx.x;
    int b = bq / NQ;
    int t = threadIdx.x;
    const float* qbase = fqry + (size_t)bq * SLICE;
    float qiv = (t < HW) ? qinv[bq * HW + t] * TEMP_INV : 0.f;
    for (int n = 0; n < NCLS; n++) {
        int bn = b * NCLS + n;
        int bqn = bq * NCLS + n;
        for (int cc = t; cc < CH; cc += 256) pb_s[cc] = pbar[bn * CH + cc];
        __syncthreads();
        float sv = 0.f;
        if (t < HW) {
            for (int cc = 0; cc < CH; cc++) sv += qbase[cc * HW + t] * pb_s[cc];
            sv *= qiv;
        }
        red_s[t] = (t < HW) ? sv : -INFINITY;
        __syncthreads();
        for (int o = 128; o >= 1; o >>= 1) {
            if (t < o) red_s[t] = fmaxf(red_s[t], red_s[t + o]);
            __syncthreads();
        }
        float mx = red_s[0];
        __syncthreads();
        float e = (t < HW) ? __expf(sv - mx) : 0.f;
        red_s[t] = e;
        __syncthreads();
        for (int o = 128; o >= 1; o >>= 1) {
            if (t < o) red_s[t] += red_s[t + o];
            __syncthreads();
        }
        float denom = red_s[0];
        __syncthreads();
        if (t < HW) aq[(size_t)bqn * HW + t] = e / denom + 1.0f;
        __syncthreads();
    }
}

// K5: write both outputs. out0[b,q,n,c,i] = proto[bn,c,i]*ap[bqn,i];
//     out1[b,q,n,c,j] = fqry[bq,c,j]*aq[bqn,j]
__global__ void k_out(const float* __restrict__ proto, const float* __restrict__ fqry,
                      const float* __restrict__ ap, const float* __restrict__ aq,
                      float* __restrict__ out) {
    const int TOT4 = (NB * NQ * NCLS * SLICE) / 4;   // 24,000,000
    const size_t OUT1 = (size_t)NB * NQ * NCLS * SLICE; // 96,000,000
    int stride = gridDim.x * blockDim.x;
    for (int v = blockIdx.x * blockDim.x + threadIdx.x; v < TOT4; v += stride) {
        int p = v * 4;
        int bqn = p / SLICE;
        int off = p - bqn * SLICE;
        int i = off % HW;                  // multiple of 4
        int bq = bqn / NCLS;
        int n = bqn - bq * NCLS;
        int b = bq / NQ;
        int bn = b * NCLS + n;

        float4 av = *reinterpret_cast<const float4*>(ap + (size_t)bqn * HW + i);
        float4 pv = *reinterpret_cast<const float4*>(proto + (size_t)bn * SLICE + off);
        float4 o0; o0.x = pv.x * av.x; o0.y = pv.y * av.y; o0.z = pv.z * av.z; o0.w = pv.w * av.w;
        *reinterpret_cast<float4*>(out + (size_t)p) = o0;

        float4 bv = *reinterpret_cast<const float4*>(aq + (size_t)bqn * HW + i);
        float4 qv = *reinterpret_cast<const float4*>(fqry + (size_t)bq * SLICE + off);
        float4 o1; o1.x = qv.x * bv.x; o1.y = qv.y * bv.y; o1.z = qv.z * bv.z; o1.w = qv.w * bv.w;
        *reinterpret_cast<float4*>(out + OUT1 + (size_t)p) = o1;
    }
}

extern "C" void kernel_launch(void* const* d_in, const int* in_sizes, int n_in,
                              void* d_out, int out_size, void* d_ws, size_t ws_size,
                              hipStream_t stream) {
    const float* fspt = (const float*)d_in[0];
    const float* fqry = (const float*)d_in[1];
    float* ws  = (float*)d_ws;
    float* out = (float*)d_out;

    float* proto = ws + OFF_PROTO;
    float* pinv  = ws + OFF_PINV;
    float* pbar  = ws + OFF_PBAR;
    float* qinv  = ws + OFF_QINV;
    float* qbar  = ws + OFF_QBAR;
    float* ap    = ws + OFF_AP;
    float* aq    = ws + OFF_AQ;

    k_proto<<<1250, 256, 0, stream>>>(fspt, proto);
    k_stats<<<NB * NCLS, 256, 0, stream>>>(proto, pinv, pbar);
    k_stats<<<NB * NQ, 256, 0, stream>>>(fqry, qinv, qbar);
    k_ap<<<NB * NCLS * 15, 256, 0, stream>>>(proto, pinv, qbar, ap);
    k_aq<<<NB * NQ, 256, 0, stream>>>(fqry, qinv, pbar, aq);
    k_out<<<2048, 256, 0, stream>>>(proto, fqry, ap, aq, out);
}

// Round 2
// 372.839 us; speedup vs baseline: 1.4812x; 1.4812x over previous
//
#include <hip/hip_runtime.h>
#include <math.h>

#define NB    4
#define NCLS  5
#define NSHOT 5
#define NQ    75
#define CH    640
#define HW    100
#define SLICE (CH*HW)          // 64000
#define TEMP_INV 4.0f
#define EPSN  1e-12f

// workspace float offsets
#define OFF_PROTO 0            // 1,280,000
#define OFF_PINV  1280000      // 2,000
#define OFF_PBAR  1282000      // 12,800
#define OFF_QINV  1294800      // 30,000
#define OFF_QBAR  1324800      // 192,000
#define OFF_AP    1516800      // 150,000
#define OFF_AQ    1666800      // 150,000
// total = 1,816,800 floats = 7.27 MB

// K1: proto[bn, cc, i] = mean over K shots of fspt
__global__ void k_proto(const float* __restrict__ fspt, float* __restrict__ proto) {
    int v = blockIdx.x * 256 + threadIdx.x;      // float4 index, 320000 total
    if (v >= (NB*NCLS*SLICE)/4) return;
    int p  = v * 4;
    int bn = p / SLICE;
    int off = p - bn * SLICE;
    size_t base = (size_t)bn * NSHOT * SLICE + off;
    float4 a = *reinterpret_cast<const float4*>(fspt + base);
    for (int k = 1; k < NSHOT; k++) {
        float4 x = *reinterpret_cast<const float4*>(fspt + base + (size_t)k * SLICE);
        a.x += x.x; a.y += x.y; a.z += x.z; a.w += x.w;
    }
    a.x *= 0.2f; a.y *= 0.2f; a.z *= 0.2f; a.w *= 0.2f;
    *reinterpret_cast<float4*>(proto + p) = a;
}

// K2: per-slice stats for proto (blk<20) and fqry (blk>=20).
// inv[s*HW+i] = 1/max(||x[:,i]||,eps); bar[s*CH+cc] = mean_i x[cc,i]*inv[i]
__global__ void k_stats(const float* __restrict__ proto, const float* __restrict__ fqry,
                        float* __restrict__ pinv, float* __restrict__ pbar,
                        float* __restrict__ qinv, float* __restrict__ qbar) {
    __shared__ float inv_s[HW];
    __shared__ float part_s[256];
    int blk = blockIdx.x;
    bool isP = blk < NB * NCLS;
    int s = isP ? blk : blk - NB * NCLS;
    const float* base = (isP ? proto : fqry) + (size_t)s * SLICE;
    float* inv = (isP ? pinv : qinv) + s * HW;
    float* bar = (isP ? pbar : qbar) + s * CH;
    int t = threadIdx.x;

    float partial = 0.f;
    if (t < 200) {
        int i  = (t < 100) ? t : t - 100;
        int c0 = (t < 100) ? 0 : CH / 2;
        const float* p = base + (size_t)c0 * HW + i;
        #pragma unroll 8
        for (int cc = 0; cc < CH / 2; cc++) { float x = p[cc * HW]; partial += x * x; }
    }
    part_s[t] = partial;
    __syncthreads();
    if (t < HW) {
        float iv = 1.0f / fmaxf(sqrtf(part_s[t] + part_s[t + 100]), EPSN);
        inv_s[t] = iv;
        inv[t] = iv;
    }
    __syncthreads();
    for (int cc = t; cc < CH; cc += 256) {
        float acc = 0.f;
        const float4* r = reinterpret_cast<const float4*>(base + (size_t)cc * HW);
        #pragma unroll
        for (int i4 = 0; i4 < HW / 4; i4++) {
            float4 x = r[i4];
            acc += x.x * inv_s[i4*4] + x.y * inv_s[i4*4+1] + x.z * inv_s[i4*4+2] + x.w * inv_s[i4*4+3];
        }
        bar[cc] = acc * (1.0f / HW);
    }
}

// K3: fused attention maps. blk<1500 -> ap[bqn], else aq[bqn-1500].
// ap[bqn,i] = softmax_i( pinv[bn,i]*4 * sum_c proto[bn,c,i]*qbar[bq,c] ) + 1
// aq[bqn,j] = softmax_j( qinv[bq,j]*4 * sum_c fqry[bq,c,j]*pbar[bn,c] ) + 1
__global__ void k_att(const float* __restrict__ proto, const float* __restrict__ fqry,
                      const float* __restrict__ pinv, const float* __restrict__ pbar,
                      const float* __restrict__ qinv, const float* __restrict__ qbar,
                      float* __restrict__ ap, float* __restrict__ aq) {
    __shared__ float vec_s[CH];
    __shared__ float part_s[256];
    __shared__ float wred[4];
    int blk = blockIdx.x;
    bool isAp = blk < NB * NQ * NCLS;
    int bqn = isAp ? blk : blk - NB * NQ * NCLS;
    int bq = bqn / NCLS;
    int n  = bqn - bq * NCLS;
    int b  = bq / NQ;
    int bn = b * NCLS + n;
    int t = threadIdx.x;

    const float* base = isAp ? proto + (size_t)bn * SLICE : fqry + (size_t)bq * SLICE;
    const float* vec  = isAp ? qbar + bq * CH : pbar + bn * CH;
    const float* invp = isAp ? pinv + bn * HW : qinv + bq * HW;
    float* dst = (isAp ? ap : aq) + (size_t)bqn * HW;

    for (int cc = t; cc < CH; cc += 256) vec_s[cc] = vec[cc];
    __syncthreads();

    float partial = 0.f;
    if (t < 200) {
        int i  = (t < 100) ? t : t - 100;
        int c0 = (t < 100) ? 0 : CH / 2;
        const float* p = base + (size_t)c0 * HW + i;
        #pragma unroll 8
        for (int cc = 0; cc < CH / 2; cc++) partial += p[cc * HW] * vec_s[c0 + cc];
    }
    part_s[t] = partial;
    __syncthreads();

    float sv = 0.f;
    if (t < HW) sv = (part_s[t] + part_s[t + 100]) * invp[t] * TEMP_INV;

    // max over the 100 values (waves 0,1 carry them; 2,3 contribute -INF)
    float mval = (t < HW) ? sv : -INFINITY;
    #pragma unroll
    for (int o = 32; o >= 1; o >>= 1) mval = fmaxf(mval, __shfl_xor(mval, o, 64));
    if ((t & 63) == 0) wred[t >> 6] = mval;
    __syncthreads();
    float mx = fmaxf(wred[0], wred[1]);

    float e = (t < HW) ? __expf(sv - mx) : 0.f;
    float sval = e;
    #pragma unroll
    for (int o = 32; o >= 1; o >>= 1) sval += __shfl_xor(sval, o, 64);
    __syncthreads();
    if ((t & 63) == 0) wred[t >> 6] = sval;
    __syncthreads();
    float denom = wred[0] + wred[1];

    if (t < HW) dst[t] = e / denom + 1.0f;
}

// K4: write both outputs. out0[b,q,n,c,i] = proto[bn,c,i]*ap[bqn,i];
//     out1[b,q,n,c,j] = fqry[bq,c,j]*aq[bqn,j]
__global__ void k_out(const float* __restrict__ proto, const float* __restrict__ fqry,
                      const float* __restrict__ ap, const float* __restrict__ aq,
                      float* __restrict__ out) {
    const int TOT4 = (NB * NQ * NCLS * SLICE) / 4;      // 24,000,000
    const size_t OUT1 = (size_t)NB * NQ * NCLS * SLICE; // 96,000,000
    int stride = gridDim.x * blockDim.x;
    for (int v = blockIdx.x * blockDim.x + threadIdx.x; v < TOT4; v += stride) {
        int p = v * 4;
        int bqn = p / SLICE;
        int off = p - bqn * SLICE;
        int i = off % HW;                  // multiple of 4
        int bq = bqn / NCLS;
        int n = bqn - bq * NCLS;
        int b = bq / NQ;
        int bn = b * NCLS + n;

        float4 av = *reinterpret_cast<const float4*>(ap + (size_t)bqn * HW + i);
        float4 pv = *reinterpret_cast<const float4*>(proto + (size_t)bn * SLICE + off);
        float4 o0; o0.x = pv.x * av.x; o0.y = pv.y * av.y; o0.z = pv.z * av.z; o0.w = pv.w * av.w;
        *reinterpret_cast<float4*>(out + (size_t)p) = o0;

        float4 bv = *reinterpret_cast<const float4*>(aq + (size_t)bqn * HW + i);
        float4 qv = *reinterpret_cast<const float4*>(fqry + (size_t)bq * SLICE + off);
        float4 o1; o1.x = qv.x * bv.x; o1.y = qv.y * bv.y; o1.z = qv.z * bv.z; o1.w = qv.w * bv.w;
        *reinterpret_cast<float4*>(out + OUT1 + (size_t)p) = o1;
    }
}

extern "C" void kernel_launch(void* const* d_in, const int* in_sizes, int n_in,
                              void* d_out, int out_size, void* d_ws, size_t ws_size,
                              hipStream_t stream) {
    const float* fspt = (const float*)d_in[0];
    const float* fqry = (const float*)d_in[1];
    float* ws  = (float*)d_ws;
    float* out = (float*)d_out;

    float* proto = ws + OFF_PROTO;
    float* pinv  = ws + OFF_PINV;
    float* pbar  = ws + OFF_PBAR;
    float* qinv  = ws + OFF_QINV;
    float* qbar  = ws + OFF_QBAR;
    float* ap    = ws + OFF_AP;
    float* aq    = ws + OFF_AQ;

    k_proto<<<1250, 256, 0, stream>>>(fspt, proto);
    k_stats<<<NB * NCLS + NB * NQ, 256, 0, stream>>>(proto, fqry, pinv, pbar, qinv, qbar);
    k_att<<<2 * NB * NQ * NCLS, 256, 0, stream>>>(proto, fqry, pinv, pbar, qinv, qbar, ap, aq);
    k_out<<<2048, 256, 0, stream>>>(proto, fqry, ap, aq, out);
}

// Round 4
// 293.714 us; speedup vs baseline: 1.8802x; 1.2694x over previous
//
#include <hip/hip_runtime.h>
#include <math.h>

#define NB    4
#define NCLS  5
#define NSHOT 5
#define NQ    75
#define CH    640
#define HW    100
#define SLICE (CH*HW)          // 64000
#define TEMP_INV 4.0f
#define EPSN  1e-12f

typedef float f32x4 __attribute__((ext_vector_type(4)));

// workspace float offsets
#define OFF_PROTO 0            // 1,280,000
#define OFF_PINV  1280000      // 2,000
#define OFF_PBAR  1282000      // 12,800
#define OFF_QINV  1294800      // 30,000
#define OFF_QBAR  1324800      // 192,000
#define OFF_AP    1516800      // 150,000
#define OFF_AQ    1666800      // 150,000

// K1: proto[bn, cc, i] = mean over K shots of fspt
__global__ void k_proto(const float* __restrict__ fspt, float* __restrict__ proto) {
    int v = blockIdx.x * 256 + threadIdx.x;      // float4 index, 320000 total
    if (v >= (NB*NCLS*SLICE)/4) return;
    int p  = v * 4;
    int bn = p / SLICE;
    int off = p - bn * SLICE;
    size_t base = (size_t)bn * NSHOT * SLICE + off;
    f32x4 a = *reinterpret_cast<const f32x4*>(fspt + base);
    for (int k = 1; k < NSHOT; k++) {
        f32x4 x = *reinterpret_cast<const f32x4*>(fspt + base + (size_t)k * SLICE);
        a += x;
    }
    a *= 0.2f;
    *reinterpret_cast<f32x4*>(proto + p) = a;
}

// K2: per-slice stats for proto (blk<20) and fqry (blk>=20).
__global__ void k_stats(const float* __restrict__ proto, const float* __restrict__ fqry,
                        float* __restrict__ pinv, float* __restrict__ pbar,
                        float* __restrict__ qinv, float* __restrict__ qbar) {
    __shared__ float inv_s[HW];
    __shared__ float part_s[256];
    int blk = blockIdx.x;
    bool isP = blk < NB * NCLS;
    int s = isP ? blk : blk - NB * NCLS;
    const float* base = (isP ? proto : fqry) + (size_t)s * SLICE;
    float* inv = (isP ? pinv : qinv) + s * HW;
    float* bar = (isP ? pbar : qbar) + s * CH;
    int t = threadIdx.x;

    float partial = 0.f;
    if (t < 200) {
        int i  = (t < 100) ? t : t - 100;
        int c0 = (t < 100) ? 0 : CH / 2;
        const float* p = base + (size_t)c0 * HW + i;
        #pragma unroll 8
        for (int cc = 0; cc < CH / 2; cc++) { float x = p[cc * HW]; partial += x * x; }
    }
    part_s[t] = partial;
    __syncthreads();
    if (t < HW) {
        float iv = 1.0f / fmaxf(sqrtf(part_s[t] + part_s[t + 100]), EPSN);
        inv_s[t] = iv;
        inv[t] = iv;
    }
    __syncthreads();
    for (int cc = t; cc < CH; cc += 256) {
        float acc = 0.f;
        const f32x4* r = reinterpret_cast<const f32x4*>(base + (size_t)cc * HW);
        #pragma unroll
        for (int i4 = 0; i4 < HW / 4; i4++) {
            f32x4 x = r[i4];
            acc += x.x * inv_s[i4*4] + x.y * inv_s[i4*4+1] + x.z * inv_s[i4*4+2] + x.w * inv_s[i4*4+3];
        }
        bar[cc] = acc * (1.0f / HW);
    }
}

// K3a: ap panels. 100 blocks = (bn, qg). Each block streams proto[bn] once,
// computes 15 q-dots per thread, then per-wave softmax over i.
// ap[bqn,i] = softmax_i( pinv[bn,i]*4 * sum_c proto[bn,c,i]*qbar[bq,c] ) + 1
__global__ void k_ap(const float* __restrict__ proto, const float* __restrict__ pinv,
                     const float* __restrict__ qbar, float* __restrict__ ap) {
    __shared__ float qb_s[15 * CH];      // 38.4 KB
    __shared__ float part_s[15][200];    // 12 KB
    __shared__ float piv_s[HW];
    int blk = blockIdx.x;
    int bn = blk / 5;
    int qg = blk - bn * 5;               // q = qg*15 + qq
    int b  = bn / NCLS;
    int t  = threadIdx.x;

    for (int qq = 0; qq < 15; qq++) {
        int bq = b * NQ + qg * 15 + qq;
        for (int cc = t; cc < CH; cc += 256) qb_s[qq * CH + cc] = qbar[bq * CH + cc];
    }
    if (t < HW) piv_s[t] = pinv[bn * HW + t] * TEMP_INV;
    __syncthreads();

    if (t < 200) {
        int i  = (t < 100) ? t : t - 100;
        int c0 = (t < 100) ? 0 : CH / 2;
        const float* p = proto + (size_t)bn * SLICE + (size_t)c0 * HW + i;
        float acc[15];
        #pragma unroll
        for (int qq = 0; qq < 15; qq++) acc[qq] = 0.f;
        for (int cc = 0; cc < CH / 2; cc++) {
            float pv = p[cc * HW];
            #pragma unroll
            for (int qq = 0; qq < 15; qq++) acc[qq] += pv * qb_s[qq * CH + c0 + cc];
        }
        #pragma unroll
        for (int qq = 0; qq < 15; qq++) part_s[qq][t] = acc[qq];
    }
    __syncthreads();

    // per-wave softmax: wave w handles qq = w, w+4, w+8, ...
    int w = t >> 6, l = t & 63;
    for (int qq = w; qq < 15; qq += 4) {
        float sv0 = (part_s[qq][l] + part_s[qq][l + 100]) * piv_s[l];           // l<64 valid i
        float sv1 = (l < 36) ? (part_s[qq][l + 64] + part_s[qq][l + 164]) * piv_s[l + 64] : -INFINITY;
        float m = fmaxf(sv0, sv1);
        #pragma unroll
        for (int o = 32; o >= 1; o >>= 1) m = fmaxf(m, __shfl_xor(m, o, 64));
        float e0 = __expf(sv0 - m);
        float e1 = (l < 36) ? __expf(sv1 - m) : 0.f;
        float sm = e0 + e1;
        #pragma unroll
        for (int o = 32; o >= 1; o >>= 1) sm += __shfl_xor(sm, o, 64);
        float inv = 1.0f / sm;
        int bqn = (b * NQ + qg * 15 + qq) * NCLS + (bn - b * NCLS);
        float* dst = ap + (size_t)bqn * HW;
        dst[l] = e0 * inv + 1.0f;
        if (l < 36) dst[l + 64] = e1 * inv + 1.0f;
    }
}

// K3b: aq panels. 300 blocks = one per bq. Streams fqry[bq] once, 5 n-dots/thread.
// aq[bqn,j] = softmax_j( qinv[bq,j]*4 * sum_c fqry[bq,c,j]*pbar[bn,c] ) + 1
__global__ void k_aq(const float* __restrict__ fqry, const float* __restrict__ qinv,
                     const float* __restrict__ pbar, float* __restrict__ aq) {
    __shared__ float pb_s[NCLS * CH];    // 12.8 KB
    __shared__ float part_s[NCLS][200];  // 4 KB
    __shared__ float qiv_s[HW];
    int bq = blockIdx.x;
    int b  = bq / NQ;
    int t  = threadIdx.x;

    for (int k = t; k < NCLS * CH; k += 256) pb_s[k] = pbar[(size_t)b * NCLS * CH + k];
    if (t < HW) qiv_s[t] = qinv[bq * HW + t] * TEMP_INV;
    __syncthreads();

    if (t < 200) {
        int i  = (t < 100) ? t : t - 100;
        int c0 = (t < 100) ? 0 : CH / 2;
        const float* p = fqry + (size_t)bq * SLICE + (size_t)c0 * HW + i;
        float acc[NCLS];
        #pragma unroll
        for (int n = 0; n < NCLS; n++) acc[n] = 0.f;
        for (int cc = 0; cc < CH / 2; cc++) {
            float pv = p[cc * HW];
            #pragma unroll
            for (int n = 0; n < NCLS; n++) acc[n] += pv * pb_s[n * CH + c0 + cc];
        }
        #pragma unroll
        for (int n = 0; n < NCLS; n++) part_s[n][t] = acc[n];
    }
    __syncthreads();

    int w = t >> 6, l = t & 63;
    for (int n = w; n < NCLS; n += 4) {
        float sv0 = (part_s[n][l] + part_s[n][l + 100]) * qiv_s[l];
        float sv1 = (l < 36) ? (part_s[n][l + 64] + part_s[n][l + 164]) * qiv_s[l + 64] : -INFINITY;
        float m = fmaxf(sv0, sv1);
        #pragma unroll
        for (int o = 32; o >= 1; o >>= 1) m = fmaxf(m, __shfl_xor(m, o, 64));
        float e0 = __expf(sv0 - m);
        float e1 = (l < 36) ? __expf(sv1 - m) : 0.f;
        float sm = e0 + e1;
        #pragma unroll
        for (int o = 32; o >= 1; o >>= 1) sm += __shfl_xor(sm, o, 64);
        float inv = 1.0f / sm;
        int bqn = bq * NCLS + n;
        float* dst = aq + (size_t)bqn * HW;
        dst[l] = e0 * inv + 1.0f;
        if (l < 36) dst[l + 64] = e1 * inv + 1.0f;
    }
}

// K4: write both outputs (nontemporal streaming stores).
__global__ void k_out(const float* __restrict__ proto, const float* __restrict__ fqry,
                      const float* __restrict__ ap, const float* __restrict__ aq,
                      float* __restrict__ out) {
    const size_t OUT1 = (size_t)NB * NQ * NCLS * SLICE; // 96,000,000
    int v = blockIdx.x * 256 + threadIdx.x;             // 24,000,000 float4
    int p = v * 4;
    int bqn = p / SLICE;
    int off = p - bqn * SLICE;
    int i = off % HW;                  // multiple of 4
    int bq = bqn / NCLS;
    int n = bqn - bq * NCLS;
    int b = bq / NQ;
    int bn = b * NCLS + n;

    f32x4 av = *reinterpret_cast<const f32x4*>(ap + (size_t)bqn * HW + i);
    f32x4 pv = *reinterpret_cast<const f32x4*>(proto + (size_t)bn * SLICE + off);
    f32x4 o0 = pv * av;
    __builtin_nontemporal_store(o0, reinterpret_cast<f32x4*>(out + (size_t)p));

    f32x4 bv = *reinterpret_cast<const f32x4*>(aq + (size_t)bqn * HW + i);
    f32x4 qv = *reinterpret_cast<const f32x4*>(fqry + (size_t)bq * SLICE + off);
    f32x4 o1 = qv * bv;
    __builtin_nontemporal_store(o1, reinterpret_cast<f32x4*>(out + OUT1 + (size_t)p));
}

extern "C" void kernel_launch(void* const* d_in, const int* in_sizes, int n_in,
                              void* d_out, int out_size, void* d_ws, size_t ws_size,
                              hipStream_t stream) {
    const float* fspt = (const float*)d_in[0];
    const float* fqry = (const float*)d_in[1];
    float* ws  = (float*)d_ws;
    float* out = (float*)d_out;

    float* proto = ws + OFF_PROTO;
    float* pinv  = ws + OFF_PINV;
    float* pbar  = ws + OFF_PBAR;
    float* qinv  = ws + OFF_QINV;
    float* qbar  = ws + OFF_QBAR;
    float* ap    = ws + OFF_AP;
    float* aq    = ws + OFF_AQ;

    k_proto<<<1250, 256, 0, stream>>>(fspt, proto);
    k_stats<<<NB * NCLS + NB * NQ, 256, 0, stream>>>(proto, fqry, pinv, pbar, qinv, qbar);
    k_ap<<<NB * NCLS * 5, 256, 0, stream>>>(proto, pinv, qbar, ap);
    k_aq<<<NB * NQ, 256, 0, stream>>>(fqry, qinv, pbar, aq);
    k_out<<<(NB * NQ * NCLS * SLICE) / 4 / 256, 256, 0, stream>>>(proto, fqry, ap, aq, out);
}

// Round 5
// 228.075 us; speedup vs baseline: 2.4213x; 1.2878x over previous
//
#include <hip/hip_runtime.h>
#include <math.h>

#define NB    4
#define NCLS  5
#define NSHOT 5
#define NQ    75
#define CH    640
#define HW    100
#define SLICE (CH*HW)          // 64000
#define TEMP_INV 4.0f
#define EPSN  1e-12f

typedef float f32x4 __attribute__((ext_vector_type(4)));

// workspace float offsets
#define OFF_PROTO 0            // 1,280,000
#define OFF_PINV  1280000      // 2,000
#define OFF_PBAR  1282000      // 12,800
#define OFF_QINV  1294800      // 30,000
#define OFF_QBAR  1324800      // 192,000
#define OFF_AP    1516800      // 150,000
#define OFF_AQ    1666800      // 150,000

// K1: proto[bn, cc, i] = mean over K shots of fspt
__global__ void k_proto(const float* __restrict__ fspt, float* __restrict__ proto) {
    int v = blockIdx.x * 256 + threadIdx.x;      // float4 index, 320000 total
    if (v >= (NB*NCLS*SLICE)/4) return;
    int p  = v * 4;
    int bn = p / SLICE;
    int off = p - bn * SLICE;
    size_t base = (size_t)bn * NSHOT * SLICE + off;
    f32x4 a = *reinterpret_cast<const f32x4*>(fspt + base);
    for (int k = 1; k < NSHOT; k++) {
        f32x4 x = *reinterpret_cast<const f32x4*>(fspt + base + (size_t)k * SLICE);
        a += x;
    }
    a *= 0.2f;
    *reinterpret_cast<f32x4*>(proto + p) = a;
}

// K2: per-slice stats for proto (blk<20) and fqry (blk>=20).
__global__ void k_stats(const float* __restrict__ proto, const float* __restrict__ fqry,
                        float* __restrict__ pinv, float* __restrict__ pbar,
                        float* __restrict__ qinv, float* __restrict__ qbar) {
    __shared__ float inv_s[HW];
    __shared__ float part_s[256];
    int blk = blockIdx.x;
    bool isP = blk < NB * NCLS;
    int s = isP ? blk : blk - NB * NCLS;
    const float* base = (isP ? proto : fqry) + (size_t)s * SLICE;
    float* inv = (isP ? pinv : qinv) + s * HW;
    float* bar = (isP ? pbar : qbar) + s * CH;
    int t = threadIdx.x;

    float partial = 0.f;
    if (t < 200) {
        int i  = (t < 100) ? t : t - 100;
        int c0 = (t < 100) ? 0 : CH / 2;
        const float* p = base + (size_t)c0 * HW + i;
        #pragma unroll 8
        for (int cc = 0; cc < CH / 2; cc++) { float x = p[cc * HW]; partial += x * x; }
    }
    part_s[t] = partial;
    __syncthreads();
    if (t < HW) {
        float iv = 1.0f / fmaxf(sqrtf(part_s[t] + part_s[t + 100]), EPSN);
        inv_s[t] = iv;
        inv[t] = iv;
    }
    __syncthreads();
    for (int cc = t; cc < CH; cc += 256) {
        float acc = 0.f;
        const f32x4* r = reinterpret_cast<const f32x4*>(base + (size_t)cc * HW);
        #pragma unroll
        for (int i4 = 0; i4 < HW / 4; i4++) {
            f32x4 x = r[i4];
            acc += x.x * inv_s[i4*4] + x.y * inv_s[i4*4+1] + x.z * inv_s[i4*4+2] + x.w * inv_s[i4*4+3];
        }
        bar[cc] = acc * (1.0f / HW);
    }
}

// K3: fused attention maps. blk<100 -> ap panel (bn,qg); blk>=100 -> aq panel (bq).
__global__ void k_att(const float* __restrict__ proto, const float* __restrict__ fqry,
                      const float* __restrict__ pinv, const float* __restrict__ pbar,
                      const float* __restrict__ qinv, const float* __restrict__ qbar,
                      float* __restrict__ ap, float* __restrict__ aq) {
    __shared__ float smem[12700];        // 50.8 KB, carved per path
    int blk = blockIdx.x;
    int t = threadIdx.x;
    int w = t >> 6, l = t & 63;

    if (blk < NB * NCLS * 5) {
        // ---- ap panel: (bn, qg), 15 q's ----
        float* qb_s   = smem;             // 15*CH = 9600
        float* part_s = smem + 9600;      // 15*200 = 3000
        float* piv_s  = smem + 12600;     // 100
        int bn = blk / 5;
        int qg = blk - bn * 5;
        int b  = bn / NCLS;

        for (int qq = 0; qq < 15; qq++) {
            int bq = b * NQ + qg * 15 + qq;
            for (int cc = t; cc < CH; cc += 256) qb_s[qq * CH + cc] = qbar[bq * CH + cc];
        }
        if (t < HW) piv_s[t] = pinv[bn * HW + t] * TEMP_INV;
        __syncthreads();

        if (t < 200) {
            int i  = (t < 100) ? t : t - 100;
            int c0 = (t < 100) ? 0 : CH / 2;
            const float* p = proto + (size_t)bn * SLICE + (size_t)c0 * HW + i;
            float acc[15];
            #pragma unroll
            for (int qq = 0; qq < 15; qq++) acc[qq] = 0.f;
            for (int cc = 0; cc < CH / 2; cc++) {
                float pv = p[cc * HW];
                #pragma unroll
                for (int qq = 0; qq < 15; qq++) acc[qq] += pv * qb_s[qq * CH + c0 + cc];
            }
            #pragma unroll
            for (int qq = 0; qq < 15; qq++) part_s[qq * 200 + t] = acc[qq];
        }
        __syncthreads();

        for (int qq = w; qq < 15; qq += 4) {
            float sv0 = (part_s[qq*200 + l] + part_s[qq*200 + l + 100]) * piv_s[l];
            float sv1 = (l < 36) ? (part_s[qq*200 + l + 64] + part_s[qq*200 + l + 164]) * piv_s[l + 64] : -INFINITY;
            float m = fmaxf(sv0, sv1);
            #pragma unroll
            for (int o = 32; o >= 1; o >>= 1) m = fmaxf(m, __shfl_xor(m, o, 64));
            float e0 = __expf(sv0 - m);
            float e1 = (l < 36) ? __expf(sv1 - m) : 0.f;
            float sm = e0 + e1;
            #pragma unroll
            for (int o = 32; o >= 1; o >>= 1) sm += __shfl_xor(sm, o, 64);
            float inv = 1.0f / sm;
            int bqn = (b * NQ + qg * 15 + qq) * NCLS + (bn - b * NCLS);
            float* dst = ap + (size_t)bqn * HW;
            dst[l] = e0 * inv + 1.0f;
            if (l < 36) dst[l + 64] = e1 * inv + 1.0f;
        }
    } else {
        // ---- aq panel: one bq, 5 n's ----
        float* pb_s   = smem;             // NCLS*CH = 3200
        float* part_s = smem + 3200;      // NCLS*200 = 1000
        float* qiv_s  = smem + 4200;      // 100
        int bq = blk - NB * NCLS * 5;
        int b  = bq / NQ;

        for (int k = t; k < NCLS * CH; k += 256) pb_s[k] = pbar[(size_t)b * NCLS * CH + k];
        if (t < HW) qiv_s[t] = qinv[bq * HW + t] * TEMP_INV;
        __syncthreads();

        if (t < 200) {
            int i  = (t < 100) ? t : t - 100;
            int c0 = (t < 100) ? 0 : CH / 2;
            const float* p = fqry + (size_t)bq * SLICE + (size_t)c0 * HW + i;
            float acc[NCLS];
            #pragma unroll
            for (int n = 0; n < NCLS; n++) acc[n] = 0.f;
            for (int cc = 0; cc < CH / 2; cc++) {
                float pv = p[cc * HW];
                #pragma unroll
                for (int n = 0; n < NCLS; n++) acc[n] += pv * pb_s[n * CH + c0 + cc];
            }
            #pragma unroll
            for (int n = 0; n < NCLS; n++) part_s[n * 200 + t] = acc[n];
        }
        __syncthreads();

        for (int n = w; n < NCLS; n += 4) {
            float sv0 = (part_s[n*200 + l] + part_s[n*200 + l + 100]) * qiv_s[l];
            float sv1 = (l < 36) ? (part_s[n*200 + l + 64] + part_s[n*200 + l + 164]) * qiv_s[l + 64] : -INFINITY;
            float m = fmaxf(sv0, sv1);
            #pragma unroll
            for (int o = 32; o >= 1; o >>= 1) m = fmaxf(m, __shfl_xor(m, o, 64));
            float e0 = __expf(sv0 - m);
            float e1 = (l < 36) ? __expf(sv1 - m) : 0.f;
            float sm = e0 + e1;
            #pragma unroll
            for (int o = 32; o >= 1; o >>= 1) sm += __shfl_xor(sm, o, 64);
            float inv = 1.0f / sm;
            int bqn = bq * NCLS + n;
            float* dst = aq + (size_t)bqn * HW;
            dst[l] = e0 * inv + 1.0f;
            if (l < 36) dst[l + 64] = e1 * inv + 1.0f;
        }
    }
}

// K4: fused output writer, register-held input, broadcast loop.
// blk<2500: out0 (bn, chunk): hold proto f4, loop 75 q.
// blk>=2500: out1 (bq, chunk): hold fqry f4, loop 5 n.
// 128 threads, chunk = 512 floats (125 chunks per slice).
__global__ void k_outs(const float* __restrict__ proto, const float* __restrict__ fqry,
                       const float* __restrict__ ap, const float* __restrict__ aq,
                       float* __restrict__ out) {
    const size_t OUT1 = (size_t)NB * NQ * NCLS * SLICE; // 96,000,000
    int blk = blockIdx.x;
    int t = threadIdx.x;

    if (blk < NB * NCLS * 125) {
        int bn = blk / 125;
        int ch = blk - bn * 125;
        int off = ch * 512 + t * 4;
        int i = off % HW;
        int b = bn / NCLS, n = bn - b * NCLS;
        f32x4 pv = *reinterpret_cast<const f32x4*>(proto + (size_t)bn * SLICE + off);
        const float* apb = ap + (size_t)(b * NQ * NCLS + n) * HW + i;
        float* ob = out + (size_t)(b * NQ * NCLS + n) * SLICE + off;
        #pragma unroll 5
        for (int q = 0; q < NQ; q++) {
            f32x4 av = *reinterpret_cast<const f32x4*>(apb + (size_t)q * NCLS * HW);
            f32x4 o = pv * av;
            __builtin_nontemporal_store(o, reinterpret_cast<f32x4*>(ob + (size_t)q * NCLS * SLICE));
        }
    } else {
        int bb = blk - NB * NCLS * 125;
        int bq = bb / 125;
        int ch = bb - bq * 125;
        int off = ch * 512 + t * 4;
        int i = off % HW;
        f32x4 qv = *reinterpret_cast<const f32x4*>(fqry + (size_t)bq * SLICE + off);
        const float* aqb = aq + (size_t)bq * NCLS * HW + i;
        float* ob = out + OUT1 + (size_t)bq * NCLS * SLICE + off;
        #pragma unroll
        for (int n = 0; n < NCLS; n++) {
            f32x4 av = *reinterpret_cast<const f32x4*>(aqb + n * HW);
            f32x4 o = qv * av;
            __builtin_nontemporal_store(o, reinterpret_cast<f32x4*>(ob + (size_t)n * SLICE));
        }
    }
}

extern "C" void kernel_launch(void* const* d_in, const int* in_sizes, int n_in,
                              void* d_out, int out_size, void* d_ws, size_t ws_size,
                              hipStream_t stream) {
    const float* fspt = (const float*)d_in[0];
    const float* fqry = (const float*)d_in[1];
    float* ws  = (float*)d_ws;
    float* out = (float*)d_out;

    float* proto = ws + OFF_PROTO;
    float* pinv  = ws + OFF_PINV;
    float* pbar  = ws + OFF_PBAR;
    float* qinv  = ws + OFF_QINV;
    float* qbar  = ws + OFF_QBAR;
    float* ap    = ws + OFF_AP;
    float* aq    = ws + OFF_AQ;

    k_proto<<<1250, 256, 0, stream>>>(fspt, proto);
    k_stats<<<NB * NCLS + NB * NQ, 256, 0, stream>>>(proto, fqry, pinv, pbar, qinv, qbar);
    k_att<<<NB * NCLS * 5 + NB * NQ, 256, 0, stream>>>(proto, fqry, pinv, pbar, qinv, qbar, ap, aq);
    k_outs<<<NB * NCLS * 125 + NB * NQ * 125, 128, 0, stream>>>(proto, fqry, ap, aq, out);
}